// Round 5
// baseline (537.024 us; speedup 1.0000x reference)
//
#include <hip/hip_runtime.h>

#define NF 128
#define NGRAPHS 64
#define NCLS 10
#define AS_STRIDE 136      // bf16 elems per LDS A-row (128 + 8 pad)
#define SCAN_THREADS 1024

typedef __attribute__((ext_vector_type(8))) short bf16x8;          // MFMA frag
typedef __attribute__((ext_vector_type(4))) float f32x4;
typedef __attribute__((ext_vector_type(8))) unsigned short u16x8;  // 16B row chunk

__device__ __forceinline__ float bf2f(unsigned short u) {
    union { unsigned int i; float f; } v; v.i = ((unsigned int)u) << 16; return v.f;
}
__device__ __forceinline__ unsigned short f2bf(float f) {
    union { float f; unsigned int i; } v; v.f = f;
    unsigned int lsb = (v.i >> 16) & 1;
    v.i += 0x7fffu + lsb;                 // RNE
    return (unsigned short)(v.i >> 16);
}

// ---------------------------------------------------------------------------
// Register-path per-node gather (round-1 form, best measured: 76 us/layer).
// r0/r2/r3 A/B established this is at the random-256B machine rate:
// 410 MB gathered / 76 us = 5.4 TB/s = ~86% of the 6.3 TB/s streaming
// ceiling — invariant to MLP depth, L2 residency, and LDS-DMA path.
// ---------------------------------------------------------------------------
__device__ __forceinline__ void gather_node(
    const unsigned short* __restrict__ x, const int* __restrict__ offs,
    const int* __restrict__ eid, int node, int n, int c, float acc[8]) {
#pragma unroll
    for (int r = 0; r < 8; ++r) acc[r] = 0.f;
    if (node >= n) return;
    int j = offs[node];
    int end = offs[node + 1];
    for (; j + 8 <= end; j += 8) {
        int s0 = eid[j + 0], s1 = eid[j + 1], s2 = eid[j + 2], s3 = eid[j + 3];
        int s4 = eid[j + 4], s5 = eid[j + 5], s6 = eid[j + 6], s7 = eid[j + 7];
        u16x8 v0 = ((const u16x8*)(x + (size_t)s0 * NF))[c];
        u16x8 v1 = ((const u16x8*)(x + (size_t)s1 * NF))[c];
        u16x8 v2 = ((const u16x8*)(x + (size_t)s2 * NF))[c];
        u16x8 v3 = ((const u16x8*)(x + (size_t)s3 * NF))[c];
        u16x8 v4 = ((const u16x8*)(x + (size_t)s4 * NF))[c];
        u16x8 v5 = ((const u16x8*)(x + (size_t)s5 * NF))[c];
        u16x8 v6 = ((const u16x8*)(x + (size_t)s6 * NF))[c];
        u16x8 v7 = ((const u16x8*)(x + (size_t)s7 * NF))[c];
#pragma unroll
        for (int r = 0; r < 8; ++r)
            acc[r] += ((bf2f(v0[r]) + bf2f(v1[r])) + (bf2f(v2[r]) + bf2f(v3[r])))
                    + ((bf2f(v4[r]) + bf2f(v5[r])) + (bf2f(v6[r]) + bf2f(v7[r])));
    }
    if (j + 4 <= end) {
        int s0 = eid[j + 0], s1 = eid[j + 1], s2 = eid[j + 2], s3 = eid[j + 3];
        u16x8 v0 = ((const u16x8*)(x + (size_t)s0 * NF))[c];
        u16x8 v1 = ((const u16x8*)(x + (size_t)s1 * NF))[c];
        u16x8 v2 = ((const u16x8*)(x + (size_t)s2 * NF))[c];
        u16x8 v3 = ((const u16x8*)(x + (size_t)s3 * NF))[c];
#pragma unroll
        for (int r = 0; r < 8; ++r)
            acc[r] += (bf2f(v0[r]) + bf2f(v1[r])) + (bf2f(v2[r]) + bf2f(v3[r]));
        j += 4;
    }
    for (; j < end; ++j) {
        int s0 = eid[j];
        u16x8 v0 = ((const u16x8*)(x + (size_t)s0 * NF))[c];
#pragma unroll
        for (int r = 0; r < 8; ++r) acc[r] += bf2f(v0[r]);
    }
}

// ---------------------------------------------------------------------------
// Streaming prep + degree histogram. degree[] is pre-zeroed by memsetAsync;
// 1.6M atomicAdd over 100K counters (mean 16/counter) rides L2 bank
// parallelism — replaces the LDS-histogram split pipeline entirely.
// ---------------------------------------------------------------------------
__global__ __launch_bounds__(256) void prep_kernel(
    const float* __restrict__ feat, unsigned short* __restrict__ featbf,
    const float* __restrict__ W1, const float* __restrict__ W2,
    unsigned short* __restrict__ Wt1, unsigned short* __restrict__ Wt2,
    float* __restrict__ sums, const int* __restrict__ dst,
    int* __restrict__ degree, int ne, int nv4) {
    int gtid = blockIdx.x * 256 + threadIdx.x;
    int nthreads = gridDim.x * 256;
    for (int i = gtid; i < nv4; i += nthreads) {
        float4 v = ((const float4*)feat)[i];
        ushort4 o;
        o.x = f2bf(v.x); o.y = f2bf(v.y); o.z = f2bf(v.z); o.w = f2bf(v.w);
        ((ushort4*)featbf)[i] = o;
    }
    for (int i = gtid; i < 2 * NF * NF; i += nthreads) {
        const float* W = (i < NF * NF) ? W1 : W2;
        unsigned short* Wt = (i < NF * NF) ? Wt1 : Wt2;
        int id = i & (NF * NF - 1);
        int f = id >> 7;
        int k = id & 127;
        Wt[f * NF + k] = f2bf(W[k * NF + f]);
    }
    for (int i = gtid; i < NGRAPHS * NF; i += nthreads) sums[i] = 0.f;
    for (int i = gtid; i < ne; i += nthreads) {
        atomicAdd(&degree[dst[i]], 1);
    }
}

// ---------------------------------------------------------------------------
// Single-block hierarchical exclusive scan of degree[0..n) -> offs, cursor.
// 1024 threads x 4 elems/iter = 4096/iter, ~25 iters for n=100K.
// ---------------------------------------------------------------------------
__global__ __launch_bounds__(SCAN_THREADS) void scan_kernel(
    const int* __restrict__ deg, int* __restrict__ offs,
    int* __restrict__ cursor, int n) {
    __shared__ int wsums[16];
    __shared__ int carry_s;
    int t = threadIdx.x;
    int lane = t & 63, w = t >> 6;
    if (t == 0) carry_s = 0;
    __syncthreads();
    for (int base = 0; base < n; base += SCAN_THREADS * 4) {
        int i0 = base + t * 4;
        int v[4];
#pragma unroll
        for (int k = 0; k < 4; ++k) {
            int i = i0 + k;
            v[k] = (i < n) ? deg[i] : 0;
        }
        int tsum = v[0] + v[1] + v[2] + v[3];
        int sc = tsum;                      // wave inclusive scan
        for (int off = 1; off < 64; off <<= 1) {
            int u = __shfl_up(sc, off, 64);
            if (lane >= off) sc += u;
        }
        if (lane == 63) wsums[w] = sc;
        __syncthreads();
        if (w == 0 && lane < 16) {          // scan the 16 wave sums
            int x = wsums[lane];
            for (int off = 1; off < 16; off <<= 1) {
                int u = __shfl_up(x, off, 64);
                if (lane >= off) x += u;
            }
            wsums[lane] = x;                // inclusive
        }
        __syncthreads();
        int wbase = (w == 0) ? 0 : wsums[w - 1];
        int excl = carry_s + wbase + (sc - tsum);
#pragma unroll
        for (int k = 0; k < 4; ++k) {
            int i = i0 + k;
            if (i < n) { offs[i] = excl; cursor[i] = excl; }
            excl += v[k];
        }
        __syncthreads();
        if (t == 0) carry_s += wsums[15];
        __syncthreads();
    }
    if (t == 0) offs[n] = carry_s;
}

// ---------------------------------------------------------------------------
// Edge scatter: counting-sort placement. pos = cursor[dst]++ via L2 atomics
// (mean 16/counter, no hotspot). Edge order within a dst is arbitrary —
// only perturbs f32 summation order in the gather (<< bf16 rounding).
// ---------------------------------------------------------------------------
__global__ __launch_bounds__(256) void scatter_kernel(
    const int* __restrict__ src, const int* __restrict__ dst,
    int* __restrict__ cursor, int* __restrict__ eid, int ne) {
    int i = blockIdx.x * 256 + threadIdx.x;
    if (i < ne) {
        int d = dst[i];
        int pos = atomicAdd(&cursor[d], 1);
        eid[pos] = src[i];
    }
}

// ---------------------------------------------------------------------------
// Fused gather + MFMA GEMM (layer 1), round-1 register path (unchanged).
// ---------------------------------------------------------------------------
__global__ __launch_bounds__(256) void gather_gemm1(
    const unsigned short* __restrict__ x, const int* __restrict__ offs,
    const int* __restrict__ eid, const unsigned short* __restrict__ Wt,
    const float* __restrict__ bias, unsigned short* __restrict__ out, int n) {
    __shared__ unsigned short As[16 * AS_STRIDE];
    int wave = threadIdx.x >> 6;
    int lane = threadIdx.x & 63;
    int q = lane >> 4;        // node selector within wave
    int c = lane & 15;        // 16B chunk / m-index
    int node_base = blockIdx.x * 16;
    int row = wave * 4 + q;   // 0..15

    float acc[8];
    gather_node(x, offs, eid, node_base + row, n, c, acc);
    {
        u16x8 o;
#pragma unroll
        for (int r = 0; r < 8; ++r) o[r] = f2bf(acc[r]);
        *(u16x8*)(&As[row * AS_STRIDE + c * 8]) = o;
    }
    __syncthreads();

    int m16 = c;
    int n0 = wave * 32;
    const unsigned short* b0r = Wt + (size_t)(n0 + m16) * NF + q * 8;
    const unsigned short* b1r = b0r + 16 * NF;
    f32x4 acc0 = {0.f, 0.f, 0.f, 0.f};
    f32x4 acc1 = {0.f, 0.f, 0.f, 0.f};
#pragma unroll
    for (int kk = 0; kk < 4; ++kk) {
        bf16x8 a  = *(const bf16x8*)(&As[m16 * AS_STRIDE + kk * 32 + q * 8]);
        bf16x8 b0 = *(const bf16x8*)(b0r + kk * 32);
        bf16x8 b1 = *(const bf16x8*)(b1r + kk * 32);
        acc0 = __builtin_amdgcn_mfma_f32_16x16x32_bf16(a, b0, acc0, 0, 0, 0);
        acc1 = __builtin_amdgcn_mfma_f32_16x16x32_bf16(a, b1, acc1, 0, 0, 0);
    }
    float bias0 = bias[n0 + m16];
    float bias1 = bias[n0 + 16 + m16];
#pragma unroll
    for (int r = 0; r < 4; ++r) {
        int node = node_base + q * 4 + r;
        if (node >= n) break;
        unsigned short* o = out + (size_t)node * NF;
        o[n0 + m16]      = f2bf(fmaxf(acc0[r] + bias0, 0.f));
        o[n0 + 16 + m16] = f2bf(fmaxf(acc1[r] + bias1, 0.f));
    }
}

// ---------------------------------------------------------------------------
// Fused gather + MFMA GEMM (layer 2) + pool epilogue (unchanged).
// ---------------------------------------------------------------------------
__global__ __launch_bounds__(256) void gather_gemm2_pool(
    const unsigned short* __restrict__ x, const int* __restrict__ offs,
    const int* __restrict__ eid, const unsigned short* __restrict__ Wt,
    const float* __restrict__ bias, const int* __restrict__ gid,
    float* __restrict__ sums, int n) {
    __shared__ unsigned short As[16 * AS_STRIDE];
    __shared__ float hblk[16][NF];
    int wave = threadIdx.x >> 6;
    int lane = threadIdx.x & 63;
    int q = lane >> 4;
    int c = lane & 15;
    int node_base = blockIdx.x * 16;
    int row = wave * 4 + q;

    float acc[8];
    gather_node(x, offs, eid, node_base + row, n, c, acc);
    {
        u16x8 o;
#pragma unroll
        for (int r = 0; r < 8; ++r) o[r] = f2bf(acc[r]);
        *(u16x8*)(&As[row * AS_STRIDE + c * 8]) = o;
    }
    __syncthreads();

    int m16 = c;
    int n0 = wave * 32;
    const unsigned short* b0r = Wt + (size_t)(n0 + m16) * NF + q * 8;
    const unsigned short* b1r = b0r + 16 * NF;
    f32x4 acc0 = {0.f, 0.f, 0.f, 0.f};
    f32x4 acc1 = {0.f, 0.f, 0.f, 0.f};
#pragma unroll
    for (int kk = 0; kk < 4; ++kk) {
        bf16x8 a  = *(const bf16x8*)(&As[m16 * AS_STRIDE + kk * 32 + q * 8]);
        bf16x8 b0 = *(const bf16x8*)(b0r + kk * 32);
        bf16x8 b1 = *(const bf16x8*)(b1r + kk * 32);
        acc0 = __builtin_amdgcn_mfma_f32_16x16x32_bf16(a, b0, acc0, 0, 0, 0);
        acc1 = __builtin_amdgcn_mfma_f32_16x16x32_bf16(a, b1, acc1, 0, 0, 0);
    }
    float bias0 = bias[n0 + m16];
    float bias1 = bias[n0 + 16 + m16];
#pragma unroll
    for (int r = 0; r < 4; ++r) {
        int rr = q * 4 + r;
        hblk[rr][n0 + m16]      = fmaxf(acc0[r] + bias0, 0.f);
        hblk[rr][n0 + 16 + m16] = fmaxf(acc1[r] + bias1, 0.f);
    }
    __syncthreads();

    int t = threadIdx.x;
    if (t < NF) {
        float accp = 0.f;
        int cur = -1;
        int lim = min(16, n - node_base);
        for (int i = 0; i < lim; ++i) {
            int g = gid[node_base + i];
            if (g != cur) {
                if (cur >= 0) atomicAdd(&sums[cur * NF + t], accp);
                accp = 0.f;
                cur = g;
            }
            accp += bf2f(f2bf(hblk[i][t]));    // keep bf16 rounding of h2 path
        }
        if (cur >= 0) atomicAdd(&sums[cur * NF + t], accp);
    }
}

__device__ __forceinline__ int lower_bound_i(const int* a, int n, int key) {
    int lo = 0, hi = n;
    while (lo < hi) {
        int mid = (lo + hi) >> 1;
        if (a[mid] < key) lo = mid + 1; else hi = mid;
    }
    return lo;
}

// ---------------------------------------------------------------------------
// Final projection: wave-parallel 128-dim dot, one wave per graph.
// ---------------------------------------------------------------------------
__global__ __launch_bounds__(64) void final_kernel(
    const float* __restrict__ sums, const int* __restrict__ gid, int n,
    const float* __restrict__ Wp, const float* __restrict__ bp,
    float* __restrict__ out) {
    __shared__ int range[2];
    int g = blockIdx.x;
    int lane = threadIdx.x;
    if (lane == 0) range[0] = lower_bound_i(gid, n, g);
    if (lane == 1) range[1] = lower_bound_i(gid, n, g + 1);
    __syncthreads();
    float cnt = fmaxf((float)(range[1] - range[0]), 1.0f);
    float inv = 1.0f / cnt;
    float s0 = sums[g * NF + lane] * inv;
    float s1 = sums[g * NF + 64 + lane] * inv;
#pragma unroll
    for (int c = 0; c < NCLS; ++c) {
        float p = s0 * Wp[lane * NCLS + c] + s1 * Wp[(64 + lane) * NCLS + c];
#pragma unroll
        for (int m = 1; m < 64; m <<= 1) p += __shfl_xor(p, m, 64);
        if (lane == 0) out[g * NCLS + c] = p + bp[c];
    }
}

extern "C" void kernel_launch(void* const* d_in, const int* in_sizes, int n_in,
                              void* d_out, int out_size, void* d_ws, size_t ws_size,
                              hipStream_t stream) {
    const float* feat = (const float*)d_in[0];
    const float* W1   = (const float*)d_in[1];
    const float* b1   = (const float*)d_in[2];
    const float* W2   = (const float*)d_in[3];
    const float* b2   = (const float*)d_in[4];
    const float* Wp   = (const float*)d_in[5];
    const float* bp   = (const float*)d_in[6];
    const int*   src  = (const int*)d_in[7];
    const int*   dst  = (const int*)d_in[8];
    const int*   gid  = (const int*)d_in[9];

    int ne = in_sizes[7];
    int n  = in_sizes[9];

    // Workspace (16B-aligned segments):
    unsigned short* featbf = (unsigned short*)d_ws;                  // n*128 u16
    unsigned short* h1     = featbf + (size_t)n * NF;                // n*128 u16
    int* eid      = (int*)(h1 + (size_t)n * NF);                     // ne
    int* degree   = eid + ne;                                        // n
    int* cursor   = degree + n;                                      // n
    int* offs     = cursor + n;                                      // n+1
    float* sums   = (float*)(offs + n + 4);                          // 64*128
    unsigned short* Wt1 = (unsigned short*)(sums + NGRAPHS * NF);    // 128*128
    unsigned short* Wt2 = Wt1 + NF * NF;                             // 128*128

    int nv4 = n * NF / 4;
    int scatterblocks = (ne + 255) / 256;
    int ggblocks = (n + 15) / 16;

    hipMemsetAsync(degree, 0, (size_t)n * sizeof(int), stream);
    prep_kernel<<<1024, 256, 0, stream>>>(
        feat, featbf, W1, W2, Wt1, Wt2, sums, dst, degree, ne, nv4);
    scan_kernel<<<1, SCAN_THREADS, 0, stream>>>(degree, offs, cursor, n);
    scatter_kernel<<<scatterblocks, 256, 0, stream>>>(src, dst, cursor, eid, ne);

    gather_gemm1<<<ggblocks, 256, 0, stream>>>(featbf, offs, eid, Wt1, b1, h1, n);
    gather_gemm2_pool<<<ggblocks, 256, 0, stream>>>(h1, offs, eid, Wt2, b2, gid, sums, n);
    final_kernel<<<NGRAPHS, 64, 0, stream>>>(sums, gid, n, Wp, bp, (float*)d_out);
}

// Round 6
// 378.069 us; speedup vs baseline: 1.4204x; 1.4204x over previous
//
#include <hip/hip_runtime.h>

#define NF 128
#define NGRAPHS 64
#define NCLS 10
#define NPARTS 256         // dst partitions, 512 nodes each (n <= 131072)
#define PART_SHIFT 9
#define PART_NODES 512
#define PART_CAP 9216      // mean 8192 + ~11 sigma slack
#define SPLIT_TILE 4096
#define AS_STRIDE 136      // bf16 elems per LDS A-row (128 + 8 pad)
#define SRC_BITS 17        // src < 2^17 (n <= 131072); record = dlocal<<17 | src
#define QCAP 2560          // per-quarter (128-node) edge cap: mean 2048 + ~11 sigma

typedef __attribute__((ext_vector_type(8))) short bf16x8;          // MFMA frag
typedef __attribute__((ext_vector_type(4))) float f32x4;
typedef __attribute__((ext_vector_type(8))) unsigned short u16x8;  // 16B row chunk

__device__ __forceinline__ float bf2f(unsigned short u) {
    union { unsigned int i; float f; } v; v.i = ((unsigned int)u) << 16; return v.f;
}
__device__ __forceinline__ unsigned short f2bf(float f) {
    union { float f; unsigned int i; } v; v.f = f;
    unsigned int lsb = (v.i >> 16) & 1;
    v.i += 0x7fffu + lsb;                 // RNE
    return (unsigned short)(v.i >> 16);
}

// ---------------------------------------------------------------------------
// Register-path per-node gather, eid served from LDS. r0/r2/r3 A/B: the
// global-load pattern here is at the random-256B machine rate (~21 GB/s/CU,
// invariant to MLP depth / L2 residency / LDS-DMA) — do not restructure.
// ---------------------------------------------------------------------------
__device__ __forceinline__ void gather_node_l(
    const unsigned short* __restrict__ x, const int* eid_l,
    int beg, int end, int c, float acc[8]) {
#pragma unroll
    for (int r = 0; r < 8; ++r) acc[r] = 0.f;
    int j = beg;
    for (; j + 8 <= end; j += 8) {
        int s0 = eid_l[j + 0], s1 = eid_l[j + 1], s2 = eid_l[j + 2], s3 = eid_l[j + 3];
        int s4 = eid_l[j + 4], s5 = eid_l[j + 5], s6 = eid_l[j + 6], s7 = eid_l[j + 7];
        u16x8 v0 = ((const u16x8*)(x + (size_t)s0 * NF))[c];
        u16x8 v1 = ((const u16x8*)(x + (size_t)s1 * NF))[c];
        u16x8 v2 = ((const u16x8*)(x + (size_t)s2 * NF))[c];
        u16x8 v3 = ((const u16x8*)(x + (size_t)s3 * NF))[c];
        u16x8 v4 = ((const u16x8*)(x + (size_t)s4 * NF))[c];
        u16x8 v5 = ((const u16x8*)(x + (size_t)s5 * NF))[c];
        u16x8 v6 = ((const u16x8*)(x + (size_t)s6 * NF))[c];
        u16x8 v7 = ((const u16x8*)(x + (size_t)s7 * NF))[c];
#pragma unroll
        for (int r = 0; r < 8; ++r)
            acc[r] += ((bf2f(v0[r]) + bf2f(v1[r])) + (bf2f(v2[r]) + bf2f(v3[r])))
                    + ((bf2f(v4[r]) + bf2f(v5[r])) + (bf2f(v6[r]) + bf2f(v7[r])));
    }
    if (j + 4 <= end) {
        int s0 = eid_l[j + 0], s1 = eid_l[j + 1], s2 = eid_l[j + 2], s3 = eid_l[j + 3];
        u16x8 v0 = ((const u16x8*)(x + (size_t)s0 * NF))[c];
        u16x8 v1 = ((const u16x8*)(x + (size_t)s1 * NF))[c];
        u16x8 v2 = ((const u16x8*)(x + (size_t)s2 * NF))[c];
        u16x8 v3 = ((const u16x8*)(x + (size_t)s3 * NF))[c];
#pragma unroll
        for (int r = 0; r < 8; ++r)
            acc[r] += (bf2f(v0[r]) + bf2f(v1[r])) + (bf2f(v2[r]) + bf2f(v3[r]));
        j += 4;
    }
    for (; j < end; ++j) {
        int s0 = eid_l[j];
        u16x8 v0 = ((const u16x8*)(x + (size_t)s0 * NF))[c];
#pragma unroll
        for (int r = 0; r < 8; ++r) acc[r] += bf2f(v0[r]);
    }
}

// ---------------------------------------------------------------------------
// Build this block's 128-node mini-CSR in LDS from the partition records.
// Replaces build_kernel: coalesced record read, LDS-only atomics/scan/scatter.
// ---------------------------------------------------------------------------
__device__ __forceinline__ void build_local_csr(
    const unsigned int* __restrict__ records, const int* __restrict__ gcur,
    int p, int quad, unsigned int* tmp, int* eid_l,
    int* deg, int* incl, int* cursor, int* nmatch_s) {
    int t = threadIdx.x;
    if (t < 128) deg[t] = 0;
    if (t == 0) *nmatch_s = 0;
    __syncthreads();
    int L = min(gcur[p], PART_CAP);
    const unsigned int* rp = records + (size_t)p * PART_CAP;
    for (int i = t; i < L; i += 256) {
        unsigned int r = rp[i];
        int d = (int)(r >> SRC_BITS);
        if ((d >> 7) == quad) {
            int pos = atomicAdd(nmatch_s, 1);
            if (pos < QCAP) {               // never in practice (+11 sigma)
                tmp[pos] = r;
                atomicAdd(&deg[d & 127], 1);
            }
        }
    }
    __syncthreads();
    int nm = min(*nmatch_s, QCAP);
    // inclusive Hillis-Steele scan of deg[0..128)
    if (t < 128) incl[t] = deg[t];
    __syncthreads();
    for (int off = 1; off < 128; off <<= 1) {
        int v = (t < 128 && t >= off) ? incl[t - off] : 0;
        __syncthreads();
        if (t < 128) incl[t] += v;
        __syncthreads();
    }
    if (t < 128) cursor[t] = incl[t] - deg[t];
    __syncthreads();
    for (int i = t; i < nm; i += 256) {
        unsigned int r = tmp[i];
        int d = (int)((r >> SRC_BITS) & 127);
        int pos = atomicAdd(&cursor[d], 1);
        eid_l[pos] = (int)(r & ((1u << SRC_BITS) - 1));
    }
    __syncthreads();
}

// ---------------------------------------------------------------------------
// Fused prep + split (round-3 proven form). gcur zeroed by prior memset.
// ---------------------------------------------------------------------------
__global__ __launch_bounds__(256) void split_prep_kernel(
    const int* __restrict__ src, const int* __restrict__ dst,
    unsigned int* __restrict__ records, int* __restrict__ gcur,
    const float* __restrict__ feat, unsigned short* __restrict__ featbf,
    const float* __restrict__ W1, const float* __restrict__ W2,
    unsigned short* __restrict__ Wt1, unsigned short* __restrict__ Wt2,
    float* __restrict__ sums, int ne, int nv4) {
    __shared__ unsigned int stage[SPLIT_TILE];  // 16 KB
    __shared__ int hcnt[NPARTS];
    __shared__ int hscan[NPARTS];
    __shared__ int hcur[NPARTS];
    __shared__ int hg[NPARTS];
    int t = threadIdx.x;
    int gtid = blockIdx.x * 256 + t;
    int nthreads = gridDim.x * 256;

    // ---- prep (grid-stride over all blocks) ----
    for (int i = gtid; i < nv4; i += nthreads) {
        float4 v = ((const float4*)feat)[i];
        ushort4 o;
        o.x = f2bf(v.x); o.y = f2bf(v.y); o.z = f2bf(v.z); o.w = f2bf(v.w);
        ((ushort4*)featbf)[i] = o;
    }
    for (int i = gtid; i < 2 * NF * NF; i += nthreads) {
        const float* W = (i < NF * NF) ? W1 : W2;
        unsigned short* Wt = (i < NF * NF) ? Wt1 : Wt2;
        int id = i & (NF * NF - 1);
        int f = id >> 7;
        int k = id & 127;
        Wt[f * NF + k] = f2bf(W[k * NF + f]);
    }
    for (int i = gtid; i < NGRAPHS * NF; i += nthreads) sums[i] = 0.f;

    // ---- split ----
    int tile0 = blockIdx.x * SPLIT_TILE;
    int cnt = min(SPLIT_TILE, ne - tile0);
    if (cnt <= 0) return;
    hcnt[t] = 0;
    __syncthreads();
    int dv[16], sv[16];
#pragma unroll
    for (int k2 = 0; k2 < 16; ++k2) {
        int i = k2 * 256 + t;
        if (i < cnt) {
            dv[k2] = dst[tile0 + i];
            sv[k2] = src[tile0 + i];
            atomicAdd(&hcnt[dv[k2] >> PART_SHIFT], 1);
        }
    }
    __syncthreads();
    hscan[t] = hcnt[t];
    __syncthreads();
    for (int off = 1; off < NPARTS; off <<= 1) {
        int v = (t >= off) ? hscan[t - off] : 0;
        __syncthreads();
        hscan[t] += v;
        __syncthreads();
    }
    hcur[t] = hscan[t] - hcnt[t];
    hg[t] = hcnt[t] ? atomicAdd(&gcur[t], hcnt[t]) : 0;
    __syncthreads();
#pragma unroll
    for (int k2 = 0; k2 < 16; ++k2) {
        int i = k2 * 256 + t;
        if (i < cnt) {
            int d = dv[k2];
            int pos = atomicAdd(&hcur[d >> PART_SHIFT], 1);
            stage[pos] = (((unsigned int)(d & (PART_NODES - 1))) << SRC_BITS)
                         | (unsigned int)sv[k2];
        }
    }
    __syncthreads();
    int grp = t >> 4;
    int lt = t & 15;
    for (int p = grp; p < NPARTS; p += 16) {
        int c = hcnt[p];
        if (c == 0) continue;
        int b = hscan[p] - c;
        int g = hg[p];
        if (g + c > PART_CAP) c = max(0, PART_CAP - g);   // never in practice
        unsigned int* outp = records + (size_t)p * PART_CAP + g;
        for (int i = lt; i < c; i += 16) outp[i] = stage[b + i];
    }
}

// ---------------------------------------------------------------------------
// Fused LDS-CSR-build + gather + MFMA GEMM (layer 1).
// Block = quarter partition (128 nodes), 784 blocks (~3.06/CU, balanced).
// 8 tiles of 16 nodes: gather -> As -> MFMA -> h1, barriers between.
// ---------------------------------------------------------------------------
__global__ __launch_bounds__(256) void gather_gemm1(
    const unsigned short* __restrict__ x, const unsigned int* __restrict__ records,
    const int* __restrict__ gcur, const unsigned short* __restrict__ Wt,
    const float* __restrict__ bias, unsigned short* __restrict__ out, int n) {
    __shared__ unsigned int tmp[QCAP];    // 10.2 KB
    __shared__ int eid_l[QCAP];           // 10.2 KB
    __shared__ int deg[128], incl[128], cursor[128];
    __shared__ int nmatch_s;
    __shared__ unsigned short As[16 * AS_STRIDE];
    int t = threadIdx.x;
    int p = blockIdx.x >> 2;
    int quad = blockIdx.x & 3;
    int node_lo = (p << PART_SHIFT) + (quad << 7);

    build_local_csr(records, gcur, p, quad, tmp, eid_l, deg, incl, cursor, &nmatch_s);

    int wave = t >> 6;
    int lane = t & 63;
    int q = lane >> 4;        // node selector within wave
    int c = lane & 15;        // 16B chunk / m-index
    int row = wave * 4 + q;   // 0..15
    int m16 = c;
    int n0 = wave * 32;
    const unsigned short* b0r = Wt + (size_t)(n0 + m16) * NF + q * 8;
    const unsigned short* b1r = b0r + 16 * NF;
    float bias0 = bias[n0 + m16];
    float bias1 = bias[n0 + 16 + m16];

    for (int tile = 0; tile < 8; ++tile) {
        int dl = tile * 16 + row;
        int node = node_lo + dl;
        float acc[8];
        if (node < n) {
            gather_node_l(x, eid_l, incl[dl] - deg[dl], incl[dl], c, acc);
        } else {
#pragma unroll
            for (int r = 0; r < 8; ++r) acc[r] = 0.f;
        }
        {
            u16x8 o;
#pragma unroll
            for (int r = 0; r < 8; ++r) o[r] = f2bf(acc[r]);
            *(u16x8*)(&As[row * AS_STRIDE + c * 8]) = o;
        }
        __syncthreads();

        f32x4 acc0 = {0.f, 0.f, 0.f, 0.f};
        f32x4 acc1 = {0.f, 0.f, 0.f, 0.f};
#pragma unroll
        for (int kk = 0; kk < 4; ++kk) {
            bf16x8 a  = *(const bf16x8*)(&As[m16 * AS_STRIDE + kk * 32 + q * 8]);
            bf16x8 b0 = *(const bf16x8*)(b0r + kk * 32);
            bf16x8 b1 = *(const bf16x8*)(b1r + kk * 32);
            acc0 = __builtin_amdgcn_mfma_f32_16x16x32_bf16(a, b0, acc0, 0, 0, 0);
            acc1 = __builtin_amdgcn_mfma_f32_16x16x32_bf16(a, b1, acc1, 0, 0, 0);
        }
#pragma unroll
        for (int r = 0; r < 4; ++r) {
            int node2 = node_lo + tile * 16 + q * 4 + r;
            if (node2 >= n) break;
            unsigned short* o = out + (size_t)node2 * NF;
            o[n0 + m16]      = f2bf(fmaxf(acc0[r] + bias0, 0.f));
            o[n0 + 16 + m16] = f2bf(fmaxf(acc1[r] + bias1, 0.f));
        }
        __syncthreads();
    }
}

// ---------------------------------------------------------------------------
// Fused LDS-CSR-build + gather + MFMA GEMM (layer 2) + pool epilogue.
// Pool accumulates in registers across tiles (nodes monotone), one atomic
// per graph-run per block. No device fences.
// ---------------------------------------------------------------------------
__global__ __launch_bounds__(256) void gather_gemm2_pool(
    const unsigned short* __restrict__ x, const unsigned int* __restrict__ records,
    const int* __restrict__ gcur, const unsigned short* __restrict__ Wt,
    const float* __restrict__ bias, const int* __restrict__ gid,
    float* __restrict__ sums, int n) {
    __shared__ unsigned int tmp[QCAP];
    __shared__ int eid_l[QCAP];
    __shared__ int deg[128], incl[128], cursor[128];
    __shared__ int nmatch_s;
    __shared__ unsigned short As[16 * AS_STRIDE];
    __shared__ float hblk[16][NF];
    int t = threadIdx.x;
    int p = blockIdx.x >> 2;
    int quad = blockIdx.x & 3;
    int node_lo = (p << PART_SHIFT) + (quad << 7);

    build_local_csr(records, gcur, p, quad, tmp, eid_l, deg, incl, cursor, &nmatch_s);

    int wave = t >> 6;
    int lane = t & 63;
    int q = lane >> 4;
    int c = lane & 15;
    int row = wave * 4 + q;
    int m16 = c;
    int n0 = wave * 32;
    const unsigned short* b0r = Wt + (size_t)(n0 + m16) * NF + q * 8;
    const unsigned short* b1r = b0r + 16 * NF;
    float bias0 = bias[n0 + m16];
    float bias1 = bias[n0 + 16 + m16];

    float accp = 0.f;          // pool accumulator (t < NF)
    int curg = -1;

    for (int tile = 0; tile < 8; ++tile) {
        int dl = tile * 16 + row;
        int node = node_lo + dl;
        float acc[8];
        if (node < n) {
            gather_node_l(x, eid_l, incl[dl] - deg[dl], incl[dl], c, acc);
        } else {
#pragma unroll
            for (int r = 0; r < 8; ++r) acc[r] = 0.f;
        }
        {
            u16x8 o;
#pragma unroll
            for (int r = 0; r < 8; ++r) o[r] = f2bf(acc[r]);
            *(u16x8*)(&As[row * AS_STRIDE + c * 8]) = o;
        }
        __syncthreads();

        f32x4 acc0 = {0.f, 0.f, 0.f, 0.f};
        f32x4 acc1 = {0.f, 0.f, 0.f, 0.f};
#pragma unroll
        for (int kk = 0; kk < 4; ++kk) {
            bf16x8 a  = *(const bf16x8*)(&As[m16 * AS_STRIDE + kk * 32 + q * 8]);
            bf16x8 b0 = *(const bf16x8*)(b0r + kk * 32);
            bf16x8 b1 = *(const bf16x8*)(b1r + kk * 32);
            acc0 = __builtin_amdgcn_mfma_f32_16x16x32_bf16(a, b0, acc0, 0, 0, 0);
            acc1 = __builtin_amdgcn_mfma_f32_16x16x32_bf16(a, b1, acc1, 0, 0, 0);
        }
#pragma unroll
        for (int r = 0; r < 4; ++r) {
            int rr = q * 4 + r;
            hblk[rr][n0 + m16]      = fmaxf(acc0[r] + bias0, 0.f);
            hblk[rr][n0 + 16 + m16] = fmaxf(acc1[r] + bias1, 0.f);
        }
        __syncthreads();

        if (t < NF) {
            int node_base = node_lo + tile * 16;
            int lim = min(16, n - node_base);
            for (int i = 0; i < lim; ++i) {
                int g = gid[node_base + i];
                if (g != curg) {
                    if (curg >= 0) atomicAdd(&sums[curg * NF + t], accp);
                    accp = 0.f;
                    curg = g;
                }
                accp += bf2f(f2bf(hblk[i][t]));   // keep bf16 rounding of h2 path
            }
        }
        __syncthreads();
    }
    if (t < NF && curg >= 0) atomicAdd(&sums[curg * NF + t], accp);
}

__device__ __forceinline__ int lower_bound_i(const int* a, int n, int key) {
    int lo = 0, hi = n;
    while (lo < hi) {
        int mid = (lo + hi) >> 1;
        if (a[mid] < key) lo = mid + 1; else hi = mid;
    }
    return lo;
}

// ---------------------------------------------------------------------------
// Final projection: wave-parallel 128-dim dot, one wave per graph.
// ---------------------------------------------------------------------------
__global__ __launch_bounds__(64) void final_kernel(
    const float* __restrict__ sums, const int* __restrict__ gid, int n,
    const float* __restrict__ Wp, const float* __restrict__ bp,
    float* __restrict__ out) {
    __shared__ int range[2];
    int g = blockIdx.x;
    int lane = threadIdx.x;
    if (lane == 0) range[0] = lower_bound_i(gid, n, g);
    if (lane == 1) range[1] = lower_bound_i(gid, n, g + 1);
    __syncthreads();
    float cnt = fmaxf((float)(range[1] - range[0]), 1.0f);
    float inv = 1.0f / cnt;
    float s0 = sums[g * NF + lane] * inv;
    float s1 = sums[g * NF + 64 + lane] * inv;
#pragma unroll
    for (int c = 0; c < NCLS; ++c) {
        float p = s0 * Wp[lane * NCLS + c] + s1 * Wp[(64 + lane) * NCLS + c];
#pragma unroll
        for (int m = 1; m < 64; m <<= 1) p += __shfl_xor(p, m, 64);
        if (lane == 0) out[g * NCLS + c] = p + bp[c];
    }
}

extern "C" void kernel_launch(void* const* d_in, const int* in_sizes, int n_in,
                              void* d_out, int out_size, void* d_ws, size_t ws_size,
                              hipStream_t stream) {
    const float* feat = (const float*)d_in[0];
    const float* W1   = (const float*)d_in[1];
    const float* b1   = (const float*)d_in[2];
    const float* W2   = (const float*)d_in[3];
    const float* b2   = (const float*)d_in[4];
    const float* Wp   = (const float*)d_in[5];
    const float* bp   = (const float*)d_in[6];
    const int*   src  = (const int*)d_in[7];
    const int*   dst  = (const int*)d_in[8];
    const int*   gid  = (const int*)d_in[9];

    int ne = in_sizes[7];
    int n  = in_sizes[9];

    // Workspace (16B-aligned segments):
    unsigned short* featbf = (unsigned short*)d_ws;                  // n*128 u16
    unsigned short* h1     = featbf + (size_t)n * NF;                // n*128 u16
    unsigned int* records = (unsigned int*)(h1 + (size_t)n * NF);    // 256*PART_CAP u32
    float* sums   = (float*)(records + (size_t)NPARTS * PART_CAP);   // 64*128
    int* gcur     = (int*)(sums + NGRAPHS * NF);                     // 256
    unsigned short* Wt1 = (unsigned short*)(gcur + NPARTS);          // 128*128
    unsigned short* Wt2 = Wt1 + NF * NF;                             // 128*128

    int nv4 = n * NF / 4;
    int splitblocks = (ne + SPLIT_TILE - 1) / SPLIT_TILE;
    int nparts = (n + PART_NODES - 1) >> PART_SHIFT;
    int ggblocks = nparts * 4;

    hipMemsetAsync(gcur, 0, NPARTS * sizeof(int), stream);
    split_prep_kernel<<<splitblocks, 256, 0, stream>>>(
        src, dst, records, gcur, feat, featbf, W1, W2, Wt1, Wt2, sums, ne, nv4);

    gather_gemm1<<<ggblocks, 256, 0, stream>>>(featbf, records, gcur, Wt1, b1, h1, n);
    gather_gemm2_pool<<<ggblocks, 256, 0, stream>>>(h1, records, gcur, Wt2, b2, gid, sums, n);
    final_kernel<<<NGRAPHS, 64, 0, stream>>>(sums, gid, n, Wp, bp, (float*)d_out);
}